// Round 8
// baseline (1064.796 us; speedup 1.0000x reference)
//
#include <hip/hip_runtime.h>
#include <math.h>

#define TT 512
#define VV 32000
#define NB 250          // blocks; 250*128 = 32000 columns
#define NTHR 512        // 8 waves
#define BCOLS 128
#define MAXIT 1000
#define CHK 50
#define NCHK (MAXIT / CHK)
#define FPSCALE 1024.0f // fixed-point scale for row-partial quantization
#define LDS_BYTES 136576

typedef float f4 __attribute__((ext_vector_type(4)));
typedef _Float16 h8 __attribute__((ext_vector_type(8)));
typedef _Float16 h2 __attribute__((ext_vector_type(2)));
typedef unsigned long long u64;

// ---- DPP wave reductions ----
template <int CTRL>
__device__ __forceinline__ float dpp_add(float x) {
  int y = __builtin_amdgcn_update_dpp(0, __builtin_bit_cast(int, x), CTRL, 0xF, 0xF, true);
  return x + __builtin_bit_cast(float, y);
}
__device__ __forceinline__ float red16(float x) {  // valid on lanes 15 mod 16
  x = dpp_add<0x111>(x); x = dpp_add<0x112>(x);
  x = dpp_add<0x114>(x); x = dpp_add<0x118>(x);
  return x;
}
__device__ __forceinline__ float red32(float x) {  // valid on lanes 31, 63
  x = red16(x); x = dpp_add<0x142>(x); return x;
}
__device__ __forceinline__ float red64(float x) {  // valid on lane 63
  x = red32(x); x = dpp_add<0x143>(x); return x;
}

__device__ __forceinline__ int fswz(int row) { return (row ^ (row >> 5)) & 15; }

__device__ __forceinline__ u64 ald(const u64* p) {
  return __hip_atomic_load(p, __ATOMIC_RELAXED, __HIP_MEMORY_SCOPE_AGENT);
}
__device__ __forceinline__ float aldf(const float* p) {
  return __hip_atomic_load(p, __ATOMIC_RELAXED, __HIP_MEMORY_SCOPE_AGENT);
}

// Single-hop all-reduce poll: count in LOW 32 (never receives value carries),
// cumulative fixed-point sum in HIGH 32 (modular; delta vs per-lane prev).
// PH must be a NAMED array with compile-time j indices (no scratch, rule #20).
#define POLL_GROUPS(PH, DQ, TARGET, STU, PENDING, CIR)                         \
  {                                                                            \
    u64 pv[8];                                                                 \
    _Pragma("unroll")                                                          \
    for (int j = 0; j < 8; ++j) pv[j] = ald(&(DQ)[64 * j + t]);                \
    unsigned pend = 0xFFu;                                                     \
    while (pend) {                                                             \
      unsigned prog = 0;                                                       \
      _Pragma("unroll")                                                        \
      for (int j = 0; j < 8; ++j) {                                            \
        if (!(pend & (1u << j))) continue;                                     \
        if (__all((unsigned)pv[j] >= (TARGET))) {                              \
          unsigned hi = (unsigned)(pv[j] >> 32);                               \
          unsigned dlt = hi - (PH)[j];                                         \
          (PH)[j] = hi;                                                        \
          float Dv = (float)dlt * (1.0f / FPSCALE);                            \
          uf[64 * j + t] = 1.f / (Dv * (1.f / VV) + 1e-16f);                   \
          asm volatile("s_waitcnt lgkmcnt(0)" ::: "memory");                   \
          if (t == 0)                                                          \
            __hip_atomic_store(&jflag[j], (int)(STU), __ATOMIC_RELEASE,        \
                               __HIP_MEMORY_SCOPE_WORKGROUP);                  \
          pend &= ~(1u << j);                                                  \
          prog = 1;                                                            \
          if ((PENDING) && j == 0) {                                           \
            unsigned eb = 0;                                                   \
            if (t == 0) eb = __builtin_bit_cast(unsigned, aldf(&errb[CIR]));   \
            eb = __builtin_amdgcn_readfirstlane(eb);                           \
            if (__builtin_bit_cast(float, eb) < 0.005f * VV) converged = true; \
          }                                                                    \
        } else {                                                               \
          pv[j] = ald(&(DQ)[64 * j + t]);                                      \
        }                                                                      \
      }                                                                        \
      if (converged) break;                                                    \
      if (pend && !prog) __builtin_amdgcn_s_sleep(1);                          \
    }                                                                          \
  }

extern "C" __global__ void __launch_bounds__(NTHR, 1)
sink_kernel(const float* __restrict__ cost, u64* __restrict__ Dsum,
            float* __restrict__ errb, float* __restrict__ lossp) {
  extern __shared__ char smem[];
  h8*       tile8  = (h8*)smem;                      // 512 x 16 chunks (swizzled), 128 KB
  float*    uf     = (float*)(smem + 131072);        // 512 f32
  float*    u_prev = (float*)(smem + 133120);        // 512 f32
  float*    vf     = (float*)(smem + 135168);        // 128 f32
  float*    v_prev = (float*)(smem + 135680);        // 128 f32
  _Float16* vh     = (_Float16*)(smem + 136192);     // 128 f16
  h8*       vh8    = (h8*)vh;
  float*    errw   = (float*)(smem + 136448);        // 16 f32
  float*    wred   = (float*)(smem + 136512);        // 8 f32
  int*      jflag  = (int*)(smem + 136544);          // 8 i32 (row-group flags)

  const int t  = threadIdx.x;
  const int b  = blockIdx.x;
  const int cB = t & 15;        // chunk (8 cols)   — row-wise map (Phase B)
  const int rB = t >> 4;        // row slice 0..31
  const int gA = t >> 5;        // col-chunk        — Phase A map
  const int sA = t & 31;        // row-within-chunk 0..31
  const int ln = t & 63;

  const float* cb = cost + (size_t)b * BCOLS;

  // ---- load tile: K~ = fp16(exp(-20 c)) ----
  for (int i = 0; i < 16; ++i) {
    int row = rB + 32 * i;
    const float* p = cb + (size_t)row * VV + cB * 8;
    f4 x0 = *(const f4*)p;
    f4 x1 = *(const f4*)(p + 4);
    h8 kk;
#pragma unroll
    for (int e = 0; e < 4; ++e) kk[e]     = (_Float16)__expf(-20.f * x0[e]);
#pragma unroll
    for (int e = 0; e < 4; ++e) kk[4 + e] = (_Float16)__expf(-20.f * x1[e]);
    tile8[row * 16 + (cB ^ fswz(row))] = kk;
  }
  uf[t] = 1.0f;  // u_bar_0 = 1
  if (t < 8) jflag[t] = 0;
  __syncthreads();

  const bool writerA = ((t & 31) == 31);
  bool converged = false;
  unsigned ph0[8], ph1[8];  // per-lane prev high-32 per parity buffer (wave 0 only)
#pragma unroll
  for (int j = 0; j < 8; ++j) { ph0[j] = 0u; ph1[j] = 0u; }

  for (int it = 0; it < MAXIT; ++it) {
    const unsigned stU = (unsigned)(it + 1);
    const bool chkc = (it > 0) && (it % CHK == 0);
    const bool pending = ((it % CHK) == 1) && (it > CHK);
    const int ciW = it / CHK - 1;
    const int ciR = (it - 1) / CHK - 1;

    if (pending) { u_prev[t] = uf[t]; __syncthreads(); }

    // ---- Phase A: acc_j = sum_rows K~ * u_bar ----
    float acc[8];
#pragma unroll
    for (int e = 0; e < 8; ++e) acc[e] = 0.f;

    if (t < 64) {
      // wave 0: sole global poller of Dsum (count==250*n fuses reduce+barrier+bcast)
      if (it == 0) {
        if (t == 0) {
#pragma unroll
          for (int j = 0; j < 8; ++j)
            __hip_atomic_store(&jflag[j], 1, __ATOMIC_RELEASE,
                               __HIP_MEMORY_SCOPE_WORKGROUP);
        }
      } else {
        const unsigned target = 250u * (unsigned)(((it - 1) >> 1) + 1);
        if (((it - 1) & 1) == 0) {
          POLL_GROUPS(ph0, Dsum, target, stU, pending, ciR)
        } else {
          POLL_GROUPS(ph1, (Dsum + TT), target, stU, pending, ciR)
        }
      }
      if (!converged) {
#pragma unroll
        for (int i = 0; i < 16; ++i) {
          int row = 32 * i + sA;
          h8 kk = tile8[row * 16 + (gA ^ fswz(row))];
          float uu = uf[row];
#pragma unroll
          for (int e = 0; e < 8; ++e) acc[e] = fmaf((float)kk[e], uu, acc[e]);
        }
      }
    } else {
      // waves 1-7: consume row-groups as wave 0 releases them (cross-wave spin: safe)
#pragma unroll 1
      for (int j = 0; j < 8; ++j) {
        while (__hip_atomic_load(&jflag[j], __ATOMIC_ACQUIRE,
                                 __HIP_MEMORY_SCOPE_WORKGROUP) != (int)stU)
          __builtin_amdgcn_s_sleep(1);
        if (pending && j == 0) {
          unsigned eb = 0;
          if (ln == 0) eb = __builtin_bit_cast(unsigned, aldf(&errb[ciR]));
          eb = __builtin_amdgcn_readfirstlane(eb);
          if (__builtin_bit_cast(float, eb) < 0.005f * VV) { converged = true; break; }
        }
#pragma unroll
        for (int ii = 0; ii < 2; ++ii) {
          int row = 64 * j + 32 * ii + sA;
          h8 kk = tile8[row * 16 + (gA ^ fswz(row))];
          float uu = uf[row];
#pragma unroll
          for (int e = 0; e < 8; ++e) acc[e] = fmaf((float)kk[e], uu, acc[e]);
        }
      }
    }
    if (converged) break;  // uniform: errb stable & identical across blocks

#pragma unroll
    for (int e = 0; e < 8; ++e) acc[e] = red32(acc[e]);

    // ---- v_bar = 1/(Sa + 1e-16); err uses OLD v ----
    if (writerA) {
      float el = 0.f;
#pragma unroll
      for (int e = 0; e < 8; ++e) {
        float sa = acc[e] * (1.f / TT);
        float vo = vf[gA * 8 + e];
        if (chkc) { el += fabsf(vo * sa - 1.f); v_prev[gA * 8 + e] = vo; }
        float nv = 1.f / (sa + 1e-16f);
        vf[gA * 8 + e] = nv;
        vh[gA * 8 + e] = (_Float16)nv;
      }
      if (chkc) errw[gA] = el;
    }
    __syncthreads();
    if (chkc) {
      if (t == 0) {
        float s = 0.f;
#pragma unroll
        for (int w = 0; w < 16; ++w) s += errw[w];
        __hip_atomic_fetch_add(&errb[ciW], s, __ATOMIC_RELAXED, __HIP_MEMORY_SCOPE_AGENT);
      }
      __syncthreads();  // drain err add before any Dsum add of this iter
    }

    // ---- Phase B: row partials -> ONE packed atomicAdd per row per block ----
    // low32 += 1 (arrival count), high32 += round(rs*1024) (fixed-point sum).
    u64* Dcur = Dsum + (size_t)(it & 1) * TT;
    h8 vv = vh8[cB];
    for (int i = 0; i < 16; ++i) {
      int row = rB + 32 * i;
      h8 kk = tile8[row * 16 + (cB ^ fswz(row))];
      float rs = 0.f;
      rs = __builtin_amdgcn_fdot2(h2{kk[0], kk[1]}, h2{vv[0], vv[1]}, rs, false);
      rs = __builtin_amdgcn_fdot2(h2{kk[2], kk[3]}, h2{vv[2], vv[3]}, rs, false);
      rs = __builtin_amdgcn_fdot2(h2{kk[4], kk[5]}, h2{vv[4], vv[5]}, rs, false);
      rs = __builtin_amdgcn_fdot2(h2{kk[6], kk[7]}, h2{vv[6], vv[7]}, rs, false);
      rs = red16(rs);
      if ((t & 15) == 15) {
        unsigned qv = (unsigned)(int)__builtin_rintf(rs * FPSCALE);
        __hip_atomic_fetch_add(&Dcur[row], ((u64)qv << 32) | 1ull,
                               __ATOMIC_RELAXED, __HIP_MEMORY_SCOPE_AGENT);
      }
    }
    // no trailing barrier: next iter's count-poll is the cross-block fence
  }

  if (converged) {  // restore pre-check state (reference exit semantics)
    __syncthreads();  // quiesce wave0's uf stash before overwrite
    uf[t] = u_prev[t];
    if (t < 128) vf[t] = v_prev[t];
    __syncthreads();
  } else {
    // MAXIT path: drain u_1000 (buffer parity (MAXIT-1)&1 = 1) into LDS
    if (t < 64) {
      const unsigned target = 250u * (unsigned)(((MAXIT - 1) >> 1) + 1);
      POLL_GROUPS(ph1, (Dsum + TT), target, (unsigned)(MAXIT + 1), false, 0)
    }
    __syncthreads();
  }

  // ---- loss partial: sum u_bar * exp(-20c) * v_bar * c over own stripe ----
  float lacc = 0.f;
  for (int i = 0; i < 16; ++i) {
    int row = rB + 32 * i;
    const float* p = cb + (size_t)row * VV + cB * 8;
    f4 x0 = *(const f4*)p;
    f4 x1 = *(const f4*)(p + 4);
    float um = uf[row];
    float inner = 0.f;
#pragma unroll
    for (int e = 0; e < 4; ++e) inner = fmaf(vf[cB * 8 + e] * __expf(-20.f * x0[e]), x0[e], inner);
#pragma unroll
    for (int e = 0; e < 4; ++e) inner = fmaf(vf[cB * 8 + 4 + e] * __expf(-20.f * x1[e]), x1[e], inner);
    lacc = fmaf(um, inner, lacc);
  }
  lacc = red64(lacc);
  if ((t & 63) == 63) wred[t >> 6] = lacc;
  __syncthreads();
  if (t == 0) {
    float s = 0.f;
#pragma unroll
    for (int w = 0; w < 8; ++w) s += wred[w];
    lossp[b] = s;
  }
}

extern "C" __global__ void prep_kernel(u64* Dsum, float* errb, float* out) {
  int gid = threadIdx.x + blockIdx.x * 256;
  if (gid < 2 * TT) Dsum[gid] = 0ull;
  if (gid < NCHK) errb[gid] = 0.f;
  if (gid == 0) out[0] = 0.f;
}

extern "C" __global__ void final_kernel(const float* __restrict__ lossp, float* __restrict__ out) {
  int t = threadIdx.x;  // 64 threads, one wave
  float s = 0.f;
  for (int i = t; i < NB; i += 64) s += lossp[i];
  s = red64(s);
  if (t == 63) out[0] = s * (100.0f / ((float)TT * (float)VV));
}

extern "C" void kernel_launch(void* const* d_in, const int* in_sizes, int n_in,
                              void* d_out, int out_size, void* d_ws, size_t ws_size,
                              hipStream_t stream) {
  const float* cost = (const float*)d_in[0];
  float* out = (float*)d_out;
  char* ws = (char*)d_ws;
  u64*   Dsum  = (u64*)ws;                 // 2*512 u64 = 8192 B (parity double-buffer)
  float* errb  = (float*)(ws + 8192);      // 20 f32
  float* lossp = (float*)(ws + 8320);      // 250 f32

  prep_kernel<<<5, 256, 0, stream>>>(Dsum, errb, out);

  (void)hipFuncSetAttribute((const void*)sink_kernel,
                            hipFuncAttributeMaxDynamicSharedMemorySize, LDS_BYTES);
  void* args[] = {(void*)&cost, (void*)&Dsum, (void*)&errb, (void*)&lossp};
  (void)hipLaunchCooperativeKernel((const void*)sink_kernel, dim3(NB), dim3(NTHR),
                                   args, LDS_BYTES, stream);

  final_kernel<<<1, 64, 0, stream>>>(lossp, out);
}

// Round 9
// 1062.398 us; speedup vs baseline: 1.0023x; 1.0023x over previous
//
#include <hip/hip_runtime.h>
#include <math.h>

#define TT 512
#define VV 32000
#define NB 250          // blocks; 250*128 = 32000 columns
#define NTHR 512        // 8 waves
#define BCOLS 128
#define MAXIT 1000
#define CHK 50
#define NCHK (MAXIT / CHK)
#define FPSCALE 1024.0f // fixed-point scale for row-partial quantization
#define LDS_BYTES 136576

typedef float f4 __attribute__((ext_vector_type(4)));
typedef _Float16 h8 __attribute__((ext_vector_type(8)));
typedef _Float16 h2 __attribute__((ext_vector_type(2)));
typedef unsigned long long u64;

// ---- DPP wave reductions ----
template <int CTRL>
__device__ __forceinline__ float dpp_add(float x) {
  int y = __builtin_amdgcn_update_dpp(0, __builtin_bit_cast(int, x), CTRL, 0xF, 0xF, true);
  return x + __builtin_bit_cast(float, y);
}
__device__ __forceinline__ float red16(float x) {  // valid on lanes 15 mod 16
  x = dpp_add<0x111>(x); x = dpp_add<0x112>(x);
  x = dpp_add<0x114>(x); x = dpp_add<0x118>(x);
  return x;
}
__device__ __forceinline__ float red32(float x) {  // valid on lanes 31, 63
  x = red16(x); x = dpp_add<0x142>(x); return x;
}
__device__ __forceinline__ float red64(float x) {  // valid on lane 63
  x = red32(x); x = dpp_add<0x143>(x); return x;
}

__device__ __forceinline__ int fswz(int row) { return (row ^ (row >> 5)) & 15; }

__device__ __forceinline__ u64 ald(const u64* p) {
  return __hip_atomic_load(p, __ATOMIC_RELAXED, __HIP_MEMORY_SCOPE_AGENT);
}
__device__ __forceinline__ float aldf(const float* p) {
  return __hip_atomic_load(p, __ATOMIC_RELAXED, __HIP_MEMORY_SCOPE_AGENT);
}

// Single-hop all-reduce poll: count in LOW 32 (never receives value carries),
// cumulative fixed-point sum in HIGH 32 (modular; delta vs per-lane prev).
// PH must be a NAMED array with compile-time j indices (no scratch, rule #20).
#define POLL_GROUPS(PH, DQ, TARGET, STU, PENDING, CIR)                         \
  {                                                                            \
    u64 pv[8];                                                                 \
    _Pragma("unroll")                                                          \
    for (int j = 0; j < 8; ++j) pv[j] = ald(&(DQ)[64 * j + t]);                \
    unsigned pend = 0xFFu;                                                     \
    while (pend) {                                                             \
      unsigned prog = 0;                                                       \
      _Pragma("unroll")                                                        \
      for (int j = 0; j < 8; ++j) {                                            \
        if (!(pend & (1u << j))) continue;                                     \
        if (__all((unsigned)pv[j] >= (TARGET))) {                              \
          unsigned hi = (unsigned)(pv[j] >> 32);                               \
          unsigned dlt = hi - (PH)[j];                                         \
          (PH)[j] = hi;                                                        \
          float Dv = (float)dlt * (1.0f / FPSCALE);                            \
          uf[64 * j + t] = 1.f / (Dv * (1.f / VV) + 1e-16f);                   \
          asm volatile("s_waitcnt lgkmcnt(0)" ::: "memory");                   \
          if (t == 0)                                                          \
            __hip_atomic_store(&jflag[j], (int)(STU), __ATOMIC_RELEASE,        \
                               __HIP_MEMORY_SCOPE_WORKGROUP);                  \
          pend &= ~(1u << j);                                                  \
          prog = 1;                                                            \
          if ((PENDING) && j == 0) {                                           \
            unsigned eb = 0;                                                   \
            if (t == 0) eb = __builtin_bit_cast(unsigned, aldf(&errb[CIR]));   \
            eb = __builtin_amdgcn_readfirstlane(eb);                           \
            if (__builtin_bit_cast(float, eb) < 0.005f * VV) converged = true; \
          }                                                                    \
        } else {                                                               \
          pv[j] = ald(&(DQ)[64 * j + t]);                                      \
        }                                                                      \
      }                                                                        \
      if (converged) break;                                                    \
      if (pend && !prog) __builtin_amdgcn_s_sleep(1);                          \
    }                                                                          \
  }

extern "C" __global__ void __launch_bounds__(NTHR, 1)
sink_kernel(const float* __restrict__ cost, u64* __restrict__ Dsum,
            float* __restrict__ errb, float* __restrict__ lossp) {
  extern __shared__ char smem[];
  h8*       tile8  = (h8*)smem;                      // 512 x 16 chunks (swizzled), 128 KB
  float*    uf     = (float*)(smem + 131072);        // 512 f32
  float*    u_prev = (float*)(smem + 133120);        // 512 f32
  float*    vf     = (float*)(smem + 135168);        // 128 f32
  float*    v_prev = (float*)(smem + 135680);        // 128 f32
  _Float16* vh     = (_Float16*)(smem + 136192);     // 128 f16
  h8*       vh8    = (h8*)vh;
  float*    errw   = (float*)(smem + 136448);        // 16 f32
  float*    wred   = (float*)(smem + 136512);        // 8 f32
  int*      jflag  = (int*)(smem + 136544);          // 8 i32 (row-group flags)

  const int t  = threadIdx.x;
  const int b  = blockIdx.x;
  const int cB = t & 15;        // chunk (8 cols)   — row-wise map (Phase B)
  const int rB = t >> 4;        // row slice 0..31
  const int gA = t >> 5;        // col-chunk        — Phase A map
  const int sA = t & 31;        // row-within-chunk 0..31
  const int ln = t & 63;

  const float* cb = cost + (size_t)b * BCOLS;

  // ---- load tile: K~ = fp16(exp(-20 c)) ----
  for (int i = 0; i < 16; ++i) {
    int row = rB + 32 * i;
    const float* p = cb + (size_t)row * VV + cB * 8;
    f4 x0 = *(const f4*)p;
    f4 x1 = *(const f4*)(p + 4);
    h8 kk;
#pragma unroll
    for (int e = 0; e < 4; ++e) kk[e]     = (_Float16)__expf(-20.f * x0[e]);
#pragma unroll
    for (int e = 0; e < 4; ++e) kk[4 + e] = (_Float16)__expf(-20.f * x1[e]);
    tile8[row * 16 + (cB ^ fswz(row))] = kk;
  }
  uf[t] = 1.0f;  // u_bar_0 = 1
  if (t < 8) jflag[t] = 0;
  __syncthreads();

  const bool writerA = ((t & 31) == 31);
  bool converged = false;
  unsigned ph0[8], ph1[8];  // per-lane prev high-32 per parity buffer (wave 0 only)
#pragma unroll
  for (int j = 0; j < 8; ++j) { ph0[j] = 0u; ph1[j] = 0u; }

  for (int it = 0; it < MAXIT; ++it) {
    const unsigned stU = (unsigned)(it + 1);
    const bool chkc = (it > 0) && (it % CHK == 0);
    const bool pending = ((it % CHK) == 1) && (it > CHK);
    const int ciW = it / CHK - 1;
    const int ciR = (it - 1) / CHK - 1;

    if (pending) { u_prev[t] = uf[t]; __syncthreads(); }

    // ---- Phase A: acc_j = sum_rows K~ * u_bar ----
    float acc[8];
#pragma unroll
    for (int e = 0; e < 8; ++e) acc[e] = 0.f;

    if (t < 64) {
      // wave 0: sole global poller of Dsum (count==250*n fuses reduce+barrier+bcast)
      if (it == 0) {
        if (t == 0) {
#pragma unroll
          for (int j = 0; j < 8; ++j)
            __hip_atomic_store(&jflag[j], 1, __ATOMIC_RELEASE,
                               __HIP_MEMORY_SCOPE_WORKGROUP);
        }
      } else {
        const unsigned target = 250u * (unsigned)(((it - 1) >> 1) + 1);
        if (((it - 1) & 1) == 0) {
          POLL_GROUPS(ph0, Dsum, target, stU, pending, ciR)
        } else {
          POLL_GROUPS(ph1, (Dsum + TT), target, stU, pending, ciR)
        }
      }
      if (!converged) {
#pragma unroll
        for (int i = 0; i < 16; ++i) {
          int row = 32 * i + sA;
          h8 kk = tile8[row * 16 + (gA ^ fswz(row))];
          float uu = uf[row];
#pragma unroll
          for (int e = 0; e < 8; ++e) acc[e] = fmaf((float)kk[e], uu, acc[e]);
        }
      }
    } else {
      // waves 1-7: consume row-groups as wave 0 releases them (cross-wave spin: safe)
#pragma unroll 1
      for (int j = 0; j < 8; ++j) {
        while (__hip_atomic_load(&jflag[j], __ATOMIC_ACQUIRE,
                                 __HIP_MEMORY_SCOPE_WORKGROUP) != (int)stU)
          __builtin_amdgcn_s_sleep(1);
        if (pending && j == 0) {
          unsigned eb = 0;
          if (ln == 0) eb = __builtin_bit_cast(unsigned, aldf(&errb[ciR]));
          eb = __builtin_amdgcn_readfirstlane(eb);
          if (__builtin_bit_cast(float, eb) < 0.005f * VV) { converged = true; break; }
        }
#pragma unroll
        for (int ii = 0; ii < 2; ++ii) {
          int row = 64 * j + 32 * ii + sA;
          h8 kk = tile8[row * 16 + (gA ^ fswz(row))];
          float uu = uf[row];
#pragma unroll
          for (int e = 0; e < 8; ++e) acc[e] = fmaf((float)kk[e], uu, acc[e]);
        }
      }
    }
    if (converged) break;  // uniform: errb stable & identical across blocks

#pragma unroll
    for (int e = 0; e < 8; ++e) acc[e] = red32(acc[e]);

    // ---- v_bar = 1/(Sa + 1e-16); err uses OLD v ----
    if (writerA) {
      float el = 0.f;
#pragma unroll
      for (int e = 0; e < 8; ++e) {
        float sa = acc[e] * (1.f / TT);
        float vo = vf[gA * 8 + e];
        if (chkc) { el += fabsf(vo * sa - 1.f); v_prev[gA * 8 + e] = vo; }
        float nv = 1.f / (sa + 1e-16f);
        vf[gA * 8 + e] = nv;
        vh[gA * 8 + e] = (_Float16)nv;
      }
      if (chkc) errw[gA] = el;
    }
    __syncthreads();
    if (chkc) {
      if (t == 0) {
        float s = 0.f;
#pragma unroll
        for (int w = 0; w < 16; ++w) s += errw[w];
        __hip_atomic_fetch_add(&errb[ciW], s, __ATOMIC_RELAXED, __HIP_MEMORY_SCOPE_AGENT);
      }
      __syncthreads();  // drain err add before any Dsum add of this iter
    }

    // ---- Phase B: row partials -> ONE packed atomicAdd per row per block ----
    // low32 += 1 (arrival count), high32 += round(rs*1024) (fixed-point sum).
    u64* Dcur = Dsum + (size_t)(it & 1) * TT;
    h8 vv = vh8[cB];
    for (int i = 0; i < 16; ++i) {
      int row = rB + 32 * i;
      h8 kk = tile8[row * 16 + (cB ^ fswz(row))];
      float rs = 0.f;
      rs = __builtin_amdgcn_fdot2(h2{kk[0], kk[1]}, h2{vv[0], vv[1]}, rs, false);
      rs = __builtin_amdgcn_fdot2(h2{kk[2], kk[3]}, h2{vv[2], vv[3]}, rs, false);
      rs = __builtin_amdgcn_fdot2(h2{kk[4], kk[5]}, h2{vv[4], vv[5]}, rs, false);
      rs = __builtin_amdgcn_fdot2(h2{kk[6], kk[7]}, h2{vv[6], vv[7]}, rs, false);
      rs = red16(rs);
      if ((t & 15) == 15) {
        unsigned qv = (unsigned)(int)__builtin_rintf(rs * FPSCALE);
        __hip_atomic_fetch_add(&Dcur[row], ((u64)qv << 32) | 1ull,
                               __ATOMIC_RELAXED, __HIP_MEMORY_SCOPE_AGENT);
      }
    }
    // no trailing barrier: next iter's count-poll is the cross-block fence
  }

  if (converged) {  // restore pre-check state (reference exit semantics)
    __syncthreads();  // quiesce wave0's uf stash before overwrite
    uf[t] = u_prev[t];
    if (t < 128) vf[t] = v_prev[t];
    __syncthreads();
  } else {
    // MAXIT path: drain u_1000 (buffer parity (MAXIT-1)&1 = 1) into LDS
    if (t < 64) {
      const unsigned target = 250u * (unsigned)(((MAXIT - 1) >> 1) + 1);
      POLL_GROUPS(ph1, (Dsum + TT), target, (unsigned)(MAXIT + 1), false, 0)
    }
    __syncthreads();
  }

  // ---- loss partial: sum u_bar * exp(-20c) * v_bar * c over own stripe ----
  float lacc = 0.f;
  for (int i = 0; i < 16; ++i) {
    int row = rB + 32 * i;
    const float* p = cb + (size_t)row * VV + cB * 8;
    f4 x0 = *(const f4*)p;
    f4 x1 = *(const f4*)(p + 4);
    float um = uf[row];
    float inner = 0.f;
#pragma unroll
    for (int e = 0; e < 4; ++e) inner = fmaf(vf[cB * 8 + e] * __expf(-20.f * x0[e]), x0[e], inner);
#pragma unroll
    for (int e = 0; e < 4; ++e) inner = fmaf(vf[cB * 8 + 4 + e] * __expf(-20.f * x1[e]), x1[e], inner);
    lacc = fmaf(um, inner, lacc);
  }
  lacc = red64(lacc);
  if ((t & 63) == 63) wred[t >> 6] = lacc;
  __syncthreads();
  if (t == 0) {
    float s = 0.f;
#pragma unroll
    for (int w = 0; w < 8; ++w) s += wred[w];
    lossp[b] = s;
  }
}

extern "C" __global__ void prep_kernel(u64* Dsum, float* errb, float* out) {
  int gid = threadIdx.x + blockIdx.x * 256;
  if (gid < 2 * TT) Dsum[gid] = 0ull;
  if (gid < NCHK) errb[gid] = 0.f;
  if (gid == 0) out[0] = 0.f;
}

extern "C" __global__ void final_kernel(const float* __restrict__ lossp, float* __restrict__ out) {
  int t = threadIdx.x;  // 64 threads, one wave
  float s = 0.f;
  for (int i = t; i < NB; i += 64) s += lossp[i];
  s = red64(s);
  if (t == 63) out[0] = s * (100.0f / ((float)TT * (float)VV));
}

extern "C" void kernel_launch(void* const* d_in, const int* in_sizes, int n_in,
                              void* d_out, int out_size, void* d_ws, size_t ws_size,
                              hipStream_t stream) {
  const float* cost = (const float*)d_in[0];
  float* out = (float*)d_out;
  char* ws = (char*)d_ws;
  u64*   Dsum  = (u64*)ws;                 // 2*512 u64 = 8192 B (parity double-buffer)
  float* errb  = (float*)(ws + 8192);      // 20 f32
  float* lossp = (float*)(ws + 8320);      // 250 f32

  prep_kernel<<<5, 256, 0, stream>>>(Dsum, errb, out);

  (void)hipFuncSetAttribute((const void*)sink_kernel,
                            hipFuncAttributeMaxDynamicSharedMemorySize, LDS_BYTES);
  void* args[] = {(void*)&cost, (void*)&Dsum, (void*)&errb, (void*)&lossp};
  (void)hipLaunchCooperativeKernel((const void*)sink_kernel, dim3(NB), dim3(NTHR),
                                   args, LDS_BYTES, stream);

  final_kernel<<<1, 64, 0, stream>>>(lossp, out);
}

// Round 10
// 1058.877 us; speedup vs baseline: 1.0056x; 1.0033x over previous
//
#include <hip/hip_runtime.h>
#include <math.h>

#define TT 512
#define VV 32000
#define NB 250          // blocks; 250*128 = 32000 columns
#define NTHR 512        // 8 waves
#define BCOLS 128
#define MAXIT 1000
#define CHK 50
#define NCHK (MAXIT / CHK)
#define FPSCALE 1024.0f // fixed-point scale for row-partial quantization
#define LDS_BYTES 136576

typedef float f4 __attribute__((ext_vector_type(4)));
typedef _Float16 h8 __attribute__((ext_vector_type(8)));
typedef _Float16 h2 __attribute__((ext_vector_type(2)));
typedef unsigned long long u64;

// ---- DPP wave reductions ----
template <int CTRL>
__device__ __forceinline__ float dpp_add(float x) {
  int y = __builtin_amdgcn_update_dpp(0, __builtin_bit_cast(int, x), CTRL, 0xF, 0xF, true);
  return x + __builtin_bit_cast(float, y);
}
__device__ __forceinline__ float red16(float x) {  // valid on lanes 15 mod 16
  x = dpp_add<0x111>(x); x = dpp_add<0x112>(x);
  x = dpp_add<0x114>(x); x = dpp_add<0x118>(x);
  return x;
}
__device__ __forceinline__ float red32(float x) {  // valid on lanes 31, 63
  x = red16(x); x = dpp_add<0x142>(x); return x;
}
__device__ __forceinline__ float red64(float x) {  // valid on lane 63
  x = red32(x); x = dpp_add<0x143>(x); return x;
}

__device__ __forceinline__ int fswz(int row) { return (row ^ (row >> 5)) & 15; }

__device__ __forceinline__ u64 ald(const u64* p) {
  return __hip_atomic_load(p, __ATOMIC_RELAXED, __HIP_MEMORY_SCOPE_AGENT);
}
__device__ __forceinline__ float aldf(const float* p) {
  return __hip_atomic_load(p, __ATOMIC_RELAXED, __HIP_MEMORY_SCOPE_AGENT);
}

// Single-hop all-reduce poll: count in LOW 32 (never receives value carries),
// cumulative fixed-point sum in HIGH 32 (modular; delta vs per-lane prev).
// PH must be a NAMED array with compile-time j indices (no scratch, rule #20).
#define POLL_GROUPS(PH, DQ, TARGET, STU, PENDING, CIR)                         \
  {                                                                            \
    u64 pv[8];                                                                 \
    _Pragma("unroll")                                                          \
    for (int j = 0; j < 8; ++j) pv[j] = ald(&(DQ)[64 * j + t]);                \
    unsigned pend = 0xFFu;                                                     \
    while (pend) {                                                             \
      unsigned prog = 0;                                                       \
      _Pragma("unroll")                                                        \
      for (int j = 0; j < 8; ++j) {                                            \
        if (!(pend & (1u << j))) continue;                                     \
        if (__all((unsigned)pv[j] >= (TARGET))) {                              \
          unsigned hi = (unsigned)(pv[j] >> 32);                               \
          unsigned dlt = hi - (PH)[j];                                         \
          (PH)[j] = hi;                                                        \
          float Dv = (float)dlt * (1.0f / FPSCALE);                            \
          uf[64 * j + t] = 1.f / (Dv * (1.f / VV) + 1e-16f);                   \
          asm volatile("s_waitcnt lgkmcnt(0)" ::: "memory");                   \
          if (t == 0)                                                          \
            __hip_atomic_store(&jflag[j], (int)(STU), __ATOMIC_RELEASE,        \
                               __HIP_MEMORY_SCOPE_WORKGROUP);                  \
          pend &= ~(1u << j);                                                  \
          prog = 1;                                                            \
          if ((PENDING) && j == 0) {                                           \
            unsigned eb = 0;                                                   \
            if (t == 0) eb = __builtin_bit_cast(unsigned, aldf(&errb[CIR]));   \
            eb = __builtin_amdgcn_readfirstlane(eb);                           \
            if (__builtin_bit_cast(float, eb) < 0.005f * VV) converged = true; \
          }                                                                    \
        } else {                                                               \
          pv[j] = ald(&(DQ)[64 * j + t]);                                      \
        }                                                                      \
      }                                                                        \
      if (converged) break;                                                    \
      if (pend && !prog) __builtin_amdgcn_s_sleep(1);                          \
    }                                                                          \
  }

extern "C" __global__ void __launch_bounds__(NTHR, 1)
sink_kernel(const float* __restrict__ cost, u64* __restrict__ Dsum,
            float* __restrict__ errb, float* __restrict__ lossp) {
  extern __shared__ char smem[];
  h8*       tile8  = (h8*)smem;                      // 512 x 16 chunks (swizzled), 128 KB
  float*    uf     = (float*)(smem + 131072);        // 512 f32
  float*    u_prev = (float*)(smem + 133120);        // 512 f32
  float*    vf     = (float*)(smem + 135168);        // 128 f32
  float*    v_prev = (float*)(smem + 135680);        // 128 f32
  _Float16* vh     = (_Float16*)(smem + 136192);     // 128 f16
  h8*       vh8    = (h8*)vh;
  float*    errw   = (float*)(smem + 136448);        // 16 f32
  float*    wred   = (float*)(smem + 136512);        // 8 f32
  int*      jflag  = (int*)(smem + 136544);          // 8 i32 (row-group flags)

  const int t  = threadIdx.x;
  const int b  = blockIdx.x;
  const int cB = t & 15;        // chunk (8 cols)   — row-wise map (Phase B)
  const int rB = t >> 4;        // row slice 0..31
  const int gA = t >> 5;        // col-chunk        — Phase A map
  const int sA = t & 31;        // row-within-chunk 0..31
  const int ln = t & 63;

  const float* cb = cost + (size_t)b * BCOLS;

  // ---- load tile: K~ = fp16(exp(-20 c)) ----
  for (int i = 0; i < 16; ++i) {
    int row = rB + 32 * i;
    const float* p = cb + (size_t)row * VV + cB * 8;
    f4 x0 = *(const f4*)p;
    f4 x1 = *(const f4*)(p + 4);
    h8 kk;
#pragma unroll
    for (int e = 0; e < 4; ++e) kk[e]     = (_Float16)__expf(-20.f * x0[e]);
#pragma unroll
    for (int e = 0; e < 4; ++e) kk[4 + e] = (_Float16)__expf(-20.f * x1[e]);
    tile8[row * 16 + (cB ^ fswz(row))] = kk;
  }
  uf[t] = 1.0f;  // u_bar_0 = 1
  if (t < 8) jflag[t] = 0;
  __syncthreads();

  const bool writerA = ((t & 31) == 31);
  bool converged = false;
  unsigned ph0[8], ph1[8];  // per-lane prev high-32 per parity buffer (wave 0 only)
#pragma unroll
  for (int j = 0; j < 8; ++j) { ph0[j] = 0u; ph1[j] = 0u; }

  for (int it = 0; it < MAXIT; ++it) {
    const unsigned stU = (unsigned)(it + 1);
    const bool chkc = (it > 0) && (it % CHK == 0);
    const bool pending = ((it % CHK) == 1) && (it > CHK);
    const int ciW = it / CHK - 1;
    const int ciR = (it - 1) / CHK - 1;

    if (pending) { u_prev[t] = uf[t]; __syncthreads(); }

    // ---- Phase A: acc_j = sum_rows K~ * u_bar ----
    float acc[8];
#pragma unroll
    for (int e = 0; e < 8; ++e) acc[e] = 0.f;

    if (t < 64) {
      // wave 0: sole global poller of Dsum (count==250*n fuses reduce+barrier+bcast)
      if (it == 0) {
        if (t == 0) {
#pragma unroll
          for (int j = 0; j < 8; ++j)
            __hip_atomic_store(&jflag[j], 1, __ATOMIC_RELEASE,
                               __HIP_MEMORY_SCOPE_WORKGROUP);
        }
      } else {
        const unsigned target = 250u * (unsigned)(((it - 1) >> 1) + 1);
        if (((it - 1) & 1) == 0) {
          POLL_GROUPS(ph0, Dsum, target, stU, pending, ciR)
        } else {
          POLL_GROUPS(ph1, (Dsum + TT), target, stU, pending, ciR)
        }
      }
      if (!converged) {
#pragma unroll
        for (int i = 0; i < 16; ++i) {
          int row = 32 * i + sA;
          h8 kk = tile8[row * 16 + (gA ^ fswz(row))];
          float uu = uf[row];
#pragma unroll
          for (int e = 0; e < 8; ++e) acc[e] = fmaf((float)kk[e], uu, acc[e]);
        }
      }
    } else {
      // waves 1-7: consume row-groups as wave 0 releases them (cross-wave spin: safe)
#pragma unroll 1
      for (int j = 0; j < 8; ++j) {
        while (__hip_atomic_load(&jflag[j], __ATOMIC_ACQUIRE,
                                 __HIP_MEMORY_SCOPE_WORKGROUP) != (int)stU)
          __builtin_amdgcn_s_sleep(1);
        if (pending && j == 0) {
          unsigned eb = 0;
          if (ln == 0) eb = __builtin_bit_cast(unsigned, aldf(&errb[ciR]));
          eb = __builtin_amdgcn_readfirstlane(eb);
          if (__builtin_bit_cast(float, eb) < 0.005f * VV) { converged = true; break; }
        }
#pragma unroll
        for (int ii = 0; ii < 2; ++ii) {
          int row = 64 * j + 32 * ii + sA;
          h8 kk = tile8[row * 16 + (gA ^ fswz(row))];
          float uu = uf[row];
#pragma unroll
          for (int e = 0; e < 8; ++e) acc[e] = fmaf((float)kk[e], uu, acc[e]);
        }
      }
    }
    if (converged) break;  // uniform: errb stable & identical across blocks

#pragma unroll
    for (int e = 0; e < 8; ++e) acc[e] = red32(acc[e]);

    // ---- v_bar = 1/(Sa + 1e-16); err uses OLD v ----
    if (writerA) {
      float el = 0.f;
#pragma unroll
      for (int e = 0; e < 8; ++e) {
        float sa = acc[e] * (1.f / TT);
        float vo = vf[gA * 8 + e];
        if (chkc) { el += fabsf(vo * sa - 1.f); v_prev[gA * 8 + e] = vo; }
        float nv = 1.f / (sa + 1e-16f);
        vf[gA * 8 + e] = nv;
        vh[gA * 8 + e] = (_Float16)nv;
      }
      if (chkc) errw[gA] = el;
    }
    __syncthreads();
    if (chkc) {
      if (t == 0) {
        float s = 0.f;
#pragma unroll
        for (int w = 0; w < 16; ++w) s += errw[w];
        __hip_atomic_fetch_add(&errb[ciW], s, __ATOMIC_RELAXED, __HIP_MEMORY_SCOPE_AGENT);
      }
      __syncthreads();  // drain err add before any Dsum add of this iter
    }

    // ---- Phase B: row partials -> ONE packed atomicAdd per row per block ----
    // low32 += 1 (arrival count), high32 += round(rs*1024) (fixed-point sum).
    u64* Dcur = Dsum + (size_t)(it & 1) * TT;
    h8 vv = vh8[cB];
    for (int i = 0; i < 16; ++i) {
      int row = rB + 32 * i;
      h8 kk = tile8[row * 16 + (cB ^ fswz(row))];
      float rs = 0.f;
      rs = __builtin_amdgcn_fdot2(h2{kk[0], kk[1]}, h2{vv[0], vv[1]}, rs, false);
      rs = __builtin_amdgcn_fdot2(h2{kk[2], kk[3]}, h2{vv[2], vv[3]}, rs, false);
      rs = __builtin_amdgcn_fdot2(h2{kk[4], kk[5]}, h2{vv[4], vv[5]}, rs, false);
      rs = __builtin_amdgcn_fdot2(h2{kk[6], kk[7]}, h2{vv[6], vv[7]}, rs, false);
      rs = red16(rs);
      if ((t & 15) == 15) {
        unsigned qv = (unsigned)(int)__builtin_rintf(rs * FPSCALE);
        __hip_atomic_fetch_add(&Dcur[row], ((u64)qv << 32) | 1ull,
                               __ATOMIC_RELAXED, __HIP_MEMORY_SCOPE_AGENT);
      }
    }
    // no trailing barrier: next iter's count-poll is the cross-block fence
  }

  if (converged) {  // restore pre-check state (reference exit semantics)
    __syncthreads();  // quiesce wave0's uf stash before overwrite
    uf[t] = u_prev[t];
    if (t < 128) vf[t] = v_prev[t];
    __syncthreads();
  } else {
    // MAXIT path: drain u_1000 (buffer parity (MAXIT-1)&1 = 1) into LDS
    if (t < 64) {
      const unsigned target = 250u * (unsigned)(((MAXIT - 1) >> 1) + 1);
      POLL_GROUPS(ph1, (Dsum + TT), target, (unsigned)(MAXIT + 1), false, 0)
    }
    __syncthreads();
  }

  // ---- loss partial: sum u_bar * exp(-20c) * v_bar * c over own stripe ----
  float lacc = 0.f;
  for (int i = 0; i < 16; ++i) {
    int row = rB + 32 * i;
    const float* p = cb + (size_t)row * VV + cB * 8;
    f4 x0 = *(const f4*)p;
    f4 x1 = *(const f4*)(p + 4);
    float um = uf[row];
    float inner = 0.f;
#pragma unroll
    for (int e = 0; e < 4; ++e) inner = fmaf(vf[cB * 8 + e] * __expf(-20.f * x0[e]), x0[e], inner);
#pragma unroll
    for (int e = 0; e < 4; ++e) inner = fmaf(vf[cB * 8 + 4 + e] * __expf(-20.f * x1[e]), x1[e], inner);
    lacc = fmaf(um, inner, lacc);
  }
  lacc = red64(lacc);
  if ((t & 63) == 63) wred[t >> 6] = lacc;
  __syncthreads();
  if (t == 0) {
    float s = 0.f;
#pragma unroll
    for (int w = 0; w < 8; ++w) s += wred[w];
    lossp[b] = s;
  }
}

extern "C" __global__ void prep_kernel(u64* Dsum, float* errb, float* out) {
  int gid = threadIdx.x + blockIdx.x * 256;
  if (gid < 2 * TT) Dsum[gid] = 0ull;
  if (gid < NCHK) errb[gid] = 0.f;
  if (gid == 0) out[0] = 0.f;
}

extern "C" __global__ void final_kernel(const float* __restrict__ lossp, float* __restrict__ out) {
  int t = threadIdx.x;  // 64 threads, one wave
  float s = 0.f;
  for (int i = t; i < NB; i += 64) s += lossp[i];
  s = red64(s);
  if (t == 63) out[0] = s * (100.0f / ((float)TT * (float)VV));
}

extern "C" void kernel_launch(void* const* d_in, const int* in_sizes, int n_in,
                              void* d_out, int out_size, void* d_ws, size_t ws_size,
                              hipStream_t stream) {
  const float* cost = (const float*)d_in[0];
  float* out = (float*)d_out;
  char* ws = (char*)d_ws;
  u64*   Dsum  = (u64*)ws;                 // 2*512 u64 = 8192 B (parity double-buffer)
  float* errb  = (float*)(ws + 8192);      // 20 f32
  float* lossp = (float*)(ws + 8320);      // 250 f32

  prep_kernel<<<5, 256, 0, stream>>>(Dsum, errb, out);

  (void)hipFuncSetAttribute((const void*)sink_kernel,
                            hipFuncAttributeMaxDynamicSharedMemorySize, LDS_BYTES);
  void* args[] = {(void*)&cost, (void*)&Dsum, (void*)&errb, (void*)&lossp};
  (void)hipLaunchCooperativeKernel((const void*)sink_kernel, dim3(NB), dim3(NTHR),
                                   args, LDS_BYTES, stream);

  final_kernel<<<1, 64, 0, stream>>>(lossp, out);
}

// Round 11
// 1058.311 us; speedup vs baseline: 1.0061x; 1.0005x over previous
//
#include <hip/hip_runtime.h>
#include <math.h>

#define TT 512
#define VV 32000
#define NB 250          // blocks; 250*128 = 32000 columns
#define NTHR 512        // 8 waves
#define BCOLS 128
#define MAXIT 1000
#define CHK 50
#define NCHK (MAXIT / CHK)
#define FPSCALE 1024.0f // fixed-point scale for row-partial quantization
#define LDS_BYTES 136576

typedef float f4 __attribute__((ext_vector_type(4)));
typedef _Float16 h8 __attribute__((ext_vector_type(8)));
typedef _Float16 h2 __attribute__((ext_vector_type(2)));
typedef unsigned long long u64;

// ---- DPP wave reductions ----
template <int CTRL>
__device__ __forceinline__ float dpp_add(float x) {
  int y = __builtin_amdgcn_update_dpp(0, __builtin_bit_cast(int, x), CTRL, 0xF, 0xF, true);
  return x + __builtin_bit_cast(float, y);
}
__device__ __forceinline__ float red16(float x) {  // valid on lanes 15 mod 16
  x = dpp_add<0x111>(x); x = dpp_add<0x112>(x);
  x = dpp_add<0x114>(x); x = dpp_add<0x118>(x);
  return x;
}
__device__ __forceinline__ float red32(float x) {  // valid on lanes 31, 63
  x = red16(x); x = dpp_add<0x142>(x); return x;
}
__device__ __forceinline__ float red64(float x) {  // valid on lane 63
  x = red32(x); x = dpp_add<0x143>(x); return x;
}

__device__ __forceinline__ int fswz(int row) { return (row ^ (row >> 5)) & 15; }

__device__ __forceinline__ u64 ald(const u64* p) {
  return __hip_atomic_load(p, __ATOMIC_RELAXED, __HIP_MEMORY_SCOPE_AGENT);
}
__device__ __forceinline__ float aldf(const float* p) {
  return __hip_atomic_load(p, __ATOMIC_RELAXED, __HIP_MEMORY_SCOPE_AGENT);
}

// Single-hop all-reduce poll: count in LOW 32 (never receives value carries),
// cumulative fixed-point sum in HIGH 32 (modular; delta vs per-lane prev).
// PH must be a NAMED array with compile-time j indices (no scratch, rule #20).
#define POLL_GROUPS(PH, DQ, TARGET, STU, PENDING, CIR)                         \
  {                                                                            \
    u64 pv[8];                                                                 \
    _Pragma("unroll")                                                          \
    for (int j = 0; j < 8; ++j) pv[j] = ald(&(DQ)[64 * j + t]);                \
    unsigned pend = 0xFFu;                                                     \
    while (pend) {                                                             \
      unsigned prog = 0;                                                       \
      _Pragma("unroll")                                                        \
      for (int j = 0; j < 8; ++j) {                                            \
        if (!(pend & (1u << j))) continue;                                     \
        if (__all((unsigned)pv[j] >= (TARGET))) {                              \
          unsigned hi = (unsigned)(pv[j] >> 32);                               \
          unsigned dlt = hi - (PH)[j];                                         \
          (PH)[j] = hi;                                                        \
          float Dv = (float)dlt * (1.0f / FPSCALE);                            \
          uf[64 * j + t] = 1.f / (Dv * (1.f / VV) + 1e-16f);                   \
          asm volatile("s_waitcnt lgkmcnt(0)" ::: "memory");                   \
          if (t == 0)                                                          \
            __hip_atomic_store(&jflag[j], (int)(STU), __ATOMIC_RELEASE,        \
                               __HIP_MEMORY_SCOPE_WORKGROUP);                  \
          pend &= ~(1u << j);                                                  \
          prog = 1;                                                            \
          if ((PENDING) && j == 0) {                                           \
            unsigned eb = 0;                                                   \
            if (t == 0) eb = __builtin_bit_cast(unsigned, aldf(&errb[CIR]));   \
            eb = __builtin_amdgcn_readfirstlane(eb);                           \
            if (__builtin_bit_cast(float, eb) < 0.005f * VV) converged = true; \
          }                                                                    \
        } else {                                                               \
          pv[j] = ald(&(DQ)[64 * j + t]);                                      \
        }                                                                      \
      }                                                                        \
      if (converged) break;                                                    \
      if (pend && !prog) __builtin_amdgcn_s_sleep(1);                          \
    }                                                                          \
  }

extern "C" __global__ void __launch_bounds__(NTHR, 1)
sink_kernel(const float* __restrict__ cost, u64* __restrict__ Dsum,
            float* __restrict__ errb, float* __restrict__ lossp) {
  extern __shared__ char smem[];
  h8*       tile8  = (h8*)smem;                      // 512 x 16 chunks (swizzled), 128 KB
  float*    uf     = (float*)(smem + 131072);        // 512 f32
  float*    u_prev = (float*)(smem + 133120);        // 512 f32
  float*    vf     = (float*)(smem + 135168);        // 128 f32
  float*    v_prev = (float*)(smem + 135680);        // 128 f32
  _Float16* vh     = (_Float16*)(smem + 136192);     // 128 f16
  h8*       vh8    = (h8*)vh;
  float*    errw   = (float*)(smem + 136448);        // 16 f32
  float*    wred   = (float*)(smem + 136512);        // 8 f32
  int*      jflag  = (int*)(smem + 136544);          // 8 i32 (row-group flags)

  const int t  = threadIdx.x;
  const int b  = blockIdx.x;
  const int cB = t & 15;        // chunk (8 cols)   — row-wise map (Phase B)
  const int rB = t >> 4;        // row slice 0..31
  const int gA = t >> 5;        // col-chunk        — Phase A map
  const int sA = t & 31;        // row-within-chunk 0..31
  const int ln = t & 63;

  const float* cb = cost + (size_t)b * BCOLS;

  // ---- load tile: K~ = fp16(exp(-20 c)) ----
  for (int i = 0; i < 16; ++i) {
    int row = rB + 32 * i;
    const float* p = cb + (size_t)row * VV + cB * 8;
    f4 x0 = *(const f4*)p;
    f4 x1 = *(const f4*)(p + 4);
    h8 kk;
#pragma unroll
    for (int e = 0; e < 4; ++e) kk[e]     = (_Float16)__expf(-20.f * x0[e]);
#pragma unroll
    for (int e = 0; e < 4; ++e) kk[4 + e] = (_Float16)__expf(-20.f * x1[e]);
    tile8[row * 16 + (cB ^ fswz(row))] = kk;
  }
  uf[t] = 1.0f;  // u_bar_0 = 1
  if (t < 8) jflag[t] = 0;
  __syncthreads();

  const bool writerA = ((t & 31) == 31);
  bool converged = false;
  unsigned ph0[8], ph1[8];  // per-lane prev high-32 per parity buffer (wave 0 only)
#pragma unroll
  for (int j = 0; j < 8; ++j) { ph0[j] = 0u; ph1[j] = 0u; }

  for (int it = 0; it < MAXIT; ++it) {
    const unsigned stU = (unsigned)(it + 1);
    const bool chkc = (it > 0) && (it % CHK == 0);
    const bool pending = ((it % CHK) == 1) && (it > CHK);
    const int ciW = it / CHK - 1;
    const int ciR = (it - 1) / CHK - 1;

    if (pending) { u_prev[t] = uf[t]; __syncthreads(); }

    // ---- Phase A: acc_j = sum_rows K~ * u_bar ----
    float acc[8];
#pragma unroll
    for (int e = 0; e < 8; ++e) acc[e] = 0.f;

    if (t < 64) {
      // wave 0: sole global poller of Dsum (count==250*n fuses reduce+barrier+bcast)
      if (it == 0) {
        if (t == 0) {
#pragma unroll
          for (int j = 0; j < 8; ++j)
            __hip_atomic_store(&jflag[j], 1, __ATOMIC_RELEASE,
                               __HIP_MEMORY_SCOPE_WORKGROUP);
        }
      } else {
        const unsigned target = 250u * (unsigned)(((it - 1) >> 1) + 1);
        if (((it - 1) & 1) == 0) {
          POLL_GROUPS(ph0, Dsum, target, stU, pending, ciR)
        } else {
          POLL_GROUPS(ph1, (Dsum + TT), target, stU, pending, ciR)
        }
      }
      if (!converged) {
#pragma unroll
        for (int i = 0; i < 16; ++i) {
          int row = 32 * i + sA;
          h8 kk = tile8[row * 16 + (gA ^ fswz(row))];
          float uu = uf[row];
#pragma unroll
          for (int e = 0; e < 8; ++e) acc[e] = fmaf((float)kk[e], uu, acc[e]);
        }
      }
    } else {
      // waves 1-7: consume row-groups as wave 0 releases them (cross-wave spin: safe)
#pragma unroll 1
      for (int j = 0; j < 8; ++j) {
        while (__hip_atomic_load(&jflag[j], __ATOMIC_ACQUIRE,
                                 __HIP_MEMORY_SCOPE_WORKGROUP) != (int)stU)
          __builtin_amdgcn_s_sleep(1);
        if (pending && j == 0) {
          unsigned eb = 0;
          if (ln == 0) eb = __builtin_bit_cast(unsigned, aldf(&errb[ciR]));
          eb = __builtin_amdgcn_readfirstlane(eb);
          if (__builtin_bit_cast(float, eb) < 0.005f * VV) { converged = true; break; }
        }
#pragma unroll
        for (int ii = 0; ii < 2; ++ii) {
          int row = 64 * j + 32 * ii + sA;
          h8 kk = tile8[row * 16 + (gA ^ fswz(row))];
          float uu = uf[row];
#pragma unroll
          for (int e = 0; e < 8; ++e) acc[e] = fmaf((float)kk[e], uu, acc[e]);
        }
      }
    }
    if (converged) break;  // uniform: errb stable & identical across blocks

#pragma unroll
    for (int e = 0; e < 8; ++e) acc[e] = red32(acc[e]);

    // ---- v_bar = 1/(Sa + 1e-16); err uses OLD v ----
    if (writerA) {
      float el = 0.f;
#pragma unroll
      for (int e = 0; e < 8; ++e) {
        float sa = acc[e] * (1.f / TT);
        float vo = vf[gA * 8 + e];
        if (chkc) { el += fabsf(vo * sa - 1.f); v_prev[gA * 8 + e] = vo; }
        float nv = 1.f / (sa + 1e-16f);
        vf[gA * 8 + e] = nv;
        vh[gA * 8 + e] = (_Float16)nv;
      }
      if (chkc) errw[gA] = el;
    }
    __syncthreads();
    if (chkc) {
      if (t == 0) {
        float s = 0.f;
#pragma unroll
        for (int w = 0; w < 16; ++w) s += errw[w];
        __hip_atomic_fetch_add(&errb[ciW], s, __ATOMIC_RELAXED, __HIP_MEMORY_SCOPE_AGENT);
      }
      __syncthreads();  // drain err add before any Dsum add of this iter
    }

    // ---- Phase B: row partials -> ONE packed atomicAdd per row per block ----
    // low32 += 1 (arrival count), high32 += round(rs*1024) (fixed-point sum).
    u64* Dcur = Dsum + (size_t)(it & 1) * TT;
    h8 vv = vh8[cB];
    for (int i = 0; i < 16; ++i) {
      int row = rB + 32 * i;
      h8 kk = tile8[row * 16 + (cB ^ fswz(row))];
      float rs = 0.f;
      rs = __builtin_amdgcn_fdot2(h2{kk[0], kk[1]}, h2{vv[0], vv[1]}, rs, false);
      rs = __builtin_amdgcn_fdot2(h2{kk[2], kk[3]}, h2{vv[2], vv[3]}, rs, false);
      rs = __builtin_amdgcn_fdot2(h2{kk[4], kk[5]}, h2{vv[4], vv[5]}, rs, false);
      rs = __builtin_amdgcn_fdot2(h2{kk[6], kk[7]}, h2{vv[6], vv[7]}, rs, false);
      rs = red16(rs);
      if ((t & 15) == 15) {
        unsigned qv = (unsigned)(int)__builtin_rintf(rs * FPSCALE);
        __hip_atomic_fetch_add(&Dcur[row], ((u64)qv << 32) | 1ull,
                               __ATOMIC_RELAXED, __HIP_MEMORY_SCOPE_AGENT);
      }
    }
    // no trailing barrier: next iter's count-poll is the cross-block fence
  }

  if (converged) {  // restore pre-check state (reference exit semantics)
    __syncthreads();  // quiesce wave0's uf stash before overwrite
    uf[t] = u_prev[t];
    if (t < 128) vf[t] = v_prev[t];
    __syncthreads();
  } else {
    // MAXIT path: drain u_1000 (buffer parity (MAXIT-1)&1 = 1) into LDS
    if (t < 64) {
      const unsigned target = 250u * (unsigned)(((MAXIT - 1) >> 1) + 1);
      POLL_GROUPS(ph1, (Dsum + TT), target, (unsigned)(MAXIT + 1), false, 0)
    }
    __syncthreads();
  }

  // ---- loss partial: sum u_bar * exp(-20c) * v_bar * c over own stripe ----
  float lacc = 0.f;
  for (int i = 0; i < 16; ++i) {
    int row = rB + 32 * i;
    const float* p = cb + (size_t)row * VV + cB * 8;
    f4 x0 = *(const f4*)p;
    f4 x1 = *(const f4*)(p + 4);
    float um = uf[row];
    float inner = 0.f;
#pragma unroll
    for (int e = 0; e < 4; ++e) inner = fmaf(vf[cB * 8 + e] * __expf(-20.f * x0[e]), x0[e], inner);
#pragma unroll
    for (int e = 0; e < 4; ++e) inner = fmaf(vf[cB * 8 + 4 + e] * __expf(-20.f * x1[e]), x1[e], inner);
    lacc = fmaf(um, inner, lacc);
  }
  lacc = red64(lacc);
  if ((t & 63) == 63) wred[t >> 6] = lacc;
  __syncthreads();
  if (t == 0) {
    float s = 0.f;
#pragma unroll
    for (int w = 0; w < 8; ++w) s += wred[w];
    lossp[b] = s;
  }
}

extern "C" __global__ void prep_kernel(u64* Dsum, float* errb, float* out) {
  int gid = threadIdx.x + blockIdx.x * 256;
  if (gid < 2 * TT) Dsum[gid] = 0ull;
  if (gid < NCHK) errb[gid] = 0.f;
  if (gid == 0) out[0] = 0.f;
}

extern "C" __global__ void final_kernel(const float* __restrict__ lossp, float* __restrict__ out) {
  int t = threadIdx.x;  // 64 threads, one wave
  float s = 0.f;
  for (int i = t; i < NB; i += 64) s += lossp[i];
  s = red64(s);
  if (t == 63) out[0] = s * (100.0f / ((float)TT * (float)VV));
}

extern "C" void kernel_launch(void* const* d_in, const int* in_sizes, int n_in,
                              void* d_out, int out_size, void* d_ws, size_t ws_size,
                              hipStream_t stream) {
  const float* cost = (const float*)d_in[0];
  float* out = (float*)d_out;
  char* ws = (char*)d_ws;
  u64*   Dsum  = (u64*)ws;                 // 2*512 u64 = 8192 B (parity double-buffer)
  float* errb  = (float*)(ws + 8192);      // 20 f32
  float* lossp = (float*)(ws + 8320);      // 250 f32

  prep_kernel<<<5, 256, 0, stream>>>(Dsum, errb, out);

  (void)hipFuncSetAttribute((const void*)sink_kernel,
                            hipFuncAttributeMaxDynamicSharedMemorySize, LDS_BYTES);
  void* args[] = {(void*)&cost, (void*)&Dsum, (void*)&errb, (void*)&lossp};
  (void)hipLaunchCooperativeKernel((const void*)sink_kernel, dim3(NB), dim3(NTHR),
                                   args, LDS_BYTES, stream);

  final_kernel<<<1, 64, 0, stream>>>(lossp, out);
}

// Round 12
// 808.847 us; speedup vs baseline: 1.3164x; 1.3084x over previous
//
#include <hip/hip_runtime.h>
#include <math.h>

#define TT 512
#define VV 32000
#define NB 250          // blocks; 250*128 = 32000 columns
#define NTHR 512        // 8 waves
#define BCOLS 128
#define MAXIT 1000
#define CHK 50
#define NCHK (MAXIT / CHK)
#define FPSCALE 1024.0f // fixed-point scale for row-partial quantization
#define WPR 2           // sub-accumulator words per row (blocks split by b&1)
#define LSTR 16         // u64 stride per word = 128 B line spread
#define SUBTGT 125u     // blocks per sub-accumulator
#define LDS_BYTES 136576

typedef float f4 __attribute__((ext_vector_type(4)));
typedef _Float16 h8 __attribute__((ext_vector_type(8)));
typedef _Float16 h2 __attribute__((ext_vector_type(2)));
typedef unsigned long long u64;

// ---- DPP wave reductions ----
template <int CTRL>
__device__ __forceinline__ float dpp_add(float x) {
  int y = __builtin_amdgcn_update_dpp(0, __builtin_bit_cast(int, x), CTRL, 0xF, 0xF, true);
  return x + __builtin_bit_cast(float, y);
}
__device__ __forceinline__ float red16(float x) {  // valid on lanes 15 mod 16
  x = dpp_add<0x111>(x); x = dpp_add<0x112>(x);
  x = dpp_add<0x114>(x); x = dpp_add<0x118>(x);
  return x;
}
__device__ __forceinline__ float red32(float x) {  // valid on lanes 31, 63
  x = red16(x); x = dpp_add<0x142>(x); return x;
}
__device__ __forceinline__ float red64(float x) {  // valid on lane 63
  x = red32(x); x = dpp_add<0x143>(x); return x;
}

__device__ __forceinline__ int fswz(int row) { return (row ^ (row >> 5)) & 15; }

__device__ __forceinline__ u64 ald(const u64* p) {
  return __hip_atomic_load(p, __ATOMIC_RELAXED, __HIP_MEMORY_SCOPE_AGENT);
}
__device__ __forceinline__ float aldf(const float* p) {
  return __hip_atomic_load(p, __ATOMIC_RELAXED, __HIP_MEMORY_SCOPE_AGENT);
}

// Single-hop all-reduce poll over 2 line-spread sub-accumulators per row.
// count in LOW 32 (value carries fall off bit 63, never reach counts),
// cumulative fixed-point sum in HIGH 32 (modular; delta vs per-lane prev).
// PHA/PHB must be NAMED arrays with compile-time j indices (rule #20).
#define POLL_GROUPS(PHA, PHB, DQ, TARGET, STU, PENDING, CIR)                   \
  {                                                                            \
    u64 pva[8], pvb[8];                                                        \
    _Pragma("unroll")                                                          \
    for (int j = 0; j < 8; ++j) {                                              \
      pva[j] = ald(&(DQ)[(size_t)((64 * j + t) * WPR + 0) * LSTR]);            \
      pvb[j] = ald(&(DQ)[(size_t)((64 * j + t) * WPR + 1) * LSTR]);            \
    }                                                                          \
    unsigned pend = 0xFFu;                                                     \
    while (pend) {                                                             \
      unsigned prog = 0;                                                       \
      _Pragma("unroll")                                                        \
      for (int j = 0; j < 8; ++j) {                                            \
        if (!(pend & (1u << j))) continue;                                     \
        bool oka = ((unsigned)pva[j] >= (TARGET));                             \
        bool okb = ((unsigned)pvb[j] >= (TARGET));                             \
        if (__all(oka && okb)) {                                               \
          unsigned hia = (unsigned)(pva[j] >> 32);                             \
          unsigned hib = (unsigned)(pvb[j] >> 32);                             \
          unsigned dlt = (hia - (PHA)[j]) + (hib - (PHB)[j]);                  \
          (PHA)[j] = hia; (PHB)[j] = hib;                                      \
          float Dv = (float)dlt * (1.0f / FPSCALE);                            \
          uf[64 * j + t] = 1.f / (Dv * (1.f / VV) + 1e-16f);                   \
          asm volatile("s_waitcnt lgkmcnt(0)" ::: "memory");                   \
          if (t == 0)                                                          \
            __hip_atomic_store(&jflag[j], (int)(STU), __ATOMIC_RELEASE,        \
                               __HIP_MEMORY_SCOPE_WORKGROUP);                  \
          pend &= ~(1u << j);                                                  \
          prog = 1;                                                            \
          if ((PENDING) && j == 0) {                                           \
            unsigned eb = 0;                                                   \
            if (t == 0) eb = __builtin_bit_cast(unsigned, aldf(&errb[CIR]));   \
            eb = __builtin_amdgcn_readfirstlane(eb);                           \
            if (__builtin_bit_cast(float, eb) < 0.005f * VV) converged = true; \
          }                                                                    \
        } else {                                                               \
          if (!oka) pva[j] = ald(&(DQ)[(size_t)((64 * j + t) * WPR + 0) * LSTR]); \
          if (!okb) pvb[j] = ald(&(DQ)[(size_t)((64 * j + t) * WPR + 1) * LSTR]); \
        }                                                                      \
      }                                                                        \
      if (converged) break;                                                    \
      if (pend && !prog) __builtin_amdgcn_s_sleep(1);                          \
    }                                                                          \
  }

extern "C" __global__ void __launch_bounds__(NTHR, 1)
sink_kernel(const float* __restrict__ cost, u64* __restrict__ Dsum,
            float* __restrict__ errb, float* __restrict__ lossp) {
  extern __shared__ char smem[];
  h8*       tile8  = (h8*)smem;                      // 512 x 16 chunks (swizzled), 128 KB
  float*    uf     = (float*)(smem + 131072);        // 512 f32
  float*    u_prev = (float*)(smem + 133120);        // 512 f32
  float*    vf     = (float*)(smem + 135168);        // 128 f32
  float*    v_prev = (float*)(smem + 135680);        // 128 f32
  _Float16* vh     = (_Float16*)(smem + 136192);     // 128 f16
  h8*       vh8    = (h8*)vh;
  float*    errw   = (float*)(smem + 136448);        // 16 f32
  float*    wred   = (float*)(smem + 136512);        // 8 f32
  int*      jflag  = (int*)(smem + 136544);          // 8 i32 (row-group flags)

  const int t  = threadIdx.x;
  const int b  = blockIdx.x;
  const int cB = t & 15;        // chunk (8 cols)   — row-wise map (Phase B)
  const int rB = t >> 4;        // row slice 0..31
  const int gA = t >> 5;        // col-chunk        — Phase A map
  const int sA = t & 31;        // row-within-chunk 0..31
  const int ln = t & 63;

  const float* cb = cost + (size_t)b * BCOLS;

  // ---- load tile: K~ = fp16(exp(-20 c)) ----
  for (int i = 0; i < 16; ++i) {
    int row = rB + 32 * i;
    const float* p = cb + (size_t)row * VV + cB * 8;
    f4 x0 = *(const f4*)p;
    f4 x1 = *(const f4*)(p + 4);
    h8 kk;
#pragma unroll
    for (int e = 0; e < 4; ++e) kk[e]     = (_Float16)__expf(-20.f * x0[e]);
#pragma unroll
    for (int e = 0; e < 4; ++e) kk[4 + e] = (_Float16)__expf(-20.f * x1[e]);
    tile8[row * 16 + (cB ^ fswz(row))] = kk;
  }
  uf[t] = 1.0f;  // u_bar_0 = 1
  if (t < 8) jflag[t] = 0;
  __syncthreads();

  const bool writerA = ((t & 31) == 31);
  bool converged = false;
  unsigned ph0a[8], ph0b[8], ph1a[8], ph1b[8];  // per-lane prev hi-32, per parity & sub
#pragma unroll
  for (int j = 0; j < 8; ++j) { ph0a[j] = 0u; ph0b[j] = 0u; ph1a[j] = 0u; ph1b[j] = 0u; }

  for (int it = 0; it < MAXIT; ++it) {
    const unsigned stU = (unsigned)(it + 1);
    const bool chkc = (it > 0) && (it % CHK == 0);
    const bool pending = ((it % CHK) == 1) && (it > CHK);
    const int ciW = it / CHK - 1;
    const int ciR = (it - 1) / CHK - 1;

    if (pending) { u_prev[t] = uf[t]; __syncthreads(); }

    // ---- Phase A: acc_j = sum_rows K~ * u_bar ----
    float acc[8];
#pragma unroll
    for (int e = 0; e < 8; ++e) acc[e] = 0.f;

    if (t < 64) {
      // wave 0: sole global poller (count==SUBTGT*n fuses reduce+barrier+bcast)
      if (it == 0) {
        if (t == 0) {
#pragma unroll
          for (int j = 0; j < 8; ++j)
            __hip_atomic_store(&jflag[j], 1, __ATOMIC_RELEASE,
                               __HIP_MEMORY_SCOPE_WORKGROUP);
        }
      } else {
        const unsigned target = SUBTGT * (unsigned)(((it - 1) >> 1) + 1);
        if (((it - 1) & 1) == 0) {
          POLL_GROUPS(ph0a, ph0b, Dsum, target, stU, pending, ciR)
        } else {
          POLL_GROUPS(ph1a, ph1b, (Dsum + (size_t)TT * WPR * LSTR), target, stU, pending, ciR)
        }
      }
      if (!converged) {
#pragma unroll
        for (int i = 0; i < 16; ++i) {
          int row = 32 * i + sA;
          h8 kk = tile8[row * 16 + (gA ^ fswz(row))];
          float uu = uf[row];
#pragma unroll
          for (int e = 0; e < 8; ++e) acc[e] = fmaf((float)kk[e], uu, acc[e]);
        }
      }
    } else {
      // waves 1-7: consume row-groups as wave 0 releases them (cross-wave spin: safe)
#pragma unroll 1
      for (int j = 0; j < 8; ++j) {
        while (__hip_atomic_load(&jflag[j], __ATOMIC_ACQUIRE,
                                 __HIP_MEMORY_SCOPE_WORKGROUP) != (int)stU)
          __builtin_amdgcn_s_sleep(1);
        if (pending && j == 0) {
          unsigned eb = 0;
          if (ln == 0) eb = __builtin_bit_cast(unsigned, aldf(&errb[ciR]));
          eb = __builtin_amdgcn_readfirstlane(eb);
          if (__builtin_bit_cast(float, eb) < 0.005f * VV) { converged = true; break; }
        }
#pragma unroll
        for (int ii = 0; ii < 2; ++ii) {
          int row = 64 * j + 32 * ii + sA;
          h8 kk = tile8[row * 16 + (gA ^ fswz(row))];
          float uu = uf[row];
#pragma unroll
          for (int e = 0; e < 8; ++e) acc[e] = fmaf((float)kk[e], uu, acc[e]);
        }
      }
    }
    if (converged) break;  // uniform: errb stable & identical across blocks

#pragma unroll
    for (int e = 0; e < 8; ++e) acc[e] = red32(acc[e]);

    // ---- v_bar = 1/(Sa + 1e-16); err uses OLD v ----
    if (writerA) {
      float el = 0.f;
#pragma unroll
      for (int e = 0; e < 8; ++e) {
        float sa = acc[e] * (1.f / TT);
        float vo = vf[gA * 8 + e];
        if (chkc) { el += fabsf(vo * sa - 1.f); v_prev[gA * 8 + e] = vo; }
        float nv = 1.f / (sa + 1e-16f);
        vf[gA * 8 + e] = nv;
        vh[gA * 8 + e] = (_Float16)nv;
      }
      if (chkc) errw[gA] = el;
    }
    __syncthreads();
    if (chkc) {
      if (t == 0) {
        float s = 0.f;
#pragma unroll
        for (int w = 0; w < 16; ++w) s += errw[w];
        __hip_atomic_fetch_add(&errb[ciW], s, __ATOMIC_RELAXED, __HIP_MEMORY_SCOPE_AGENT);
      }
      __syncthreads();  // drain err add before any Dsum add of this iter
    }

    // ---- Phase B: row partials -> ONE packed atomicAdd per row per block ----
    // word = (row, b&1), each on its own 128B line: 125-way (not 2000-way)
    // per-line RMW serialization. low32 += 1 arrival, high32 += q (mod 2^32).
    u64* Dcur = Dsum + (size_t)(it & 1) * TT * WPR * LSTR;
    const int sub = b & 1;
    h8 vv = vh8[cB];
    for (int i = 0; i < 16; ++i) {
      int row = rB + 32 * i;
      h8 kk = tile8[row * 16 + (cB ^ fswz(row))];
      float rs = 0.f;
      rs = __builtin_amdgcn_fdot2(h2{kk[0], kk[1]}, h2{vv[0], vv[1]}, rs, false);
      rs = __builtin_amdgcn_fdot2(h2{kk[2], kk[3]}, h2{vv[2], vv[3]}, rs, false);
      rs = __builtin_amdgcn_fdot2(h2{kk[4], kk[5]}, h2{vv[4], vv[5]}, rs, false);
      rs = __builtin_amdgcn_fdot2(h2{kk[6], kk[7]}, h2{vv[6], vv[7]}, rs, false);
      rs = red16(rs);
      if ((t & 15) == 15) {
        unsigned qv = (unsigned)(int)__builtin_rintf(rs * FPSCALE);
        __hip_atomic_fetch_add(&Dcur[(size_t)(row * WPR + sub) * LSTR],
                               ((u64)qv << 32) | 1ull,
                               __ATOMIC_RELAXED, __HIP_MEMORY_SCOPE_AGENT);
      }
    }
    // no trailing barrier: next iter's count-poll is the cross-block fence
  }

  if (converged) {  // restore pre-check state (reference exit semantics)
    __syncthreads();  // quiesce wave0's uf stash before overwrite
    uf[t] = u_prev[t];
    if (t < 128) vf[t] = v_prev[t];
    __syncthreads();
  } else {
    // MAXIT path: drain u_1000 (buffer parity (MAXIT-1)&1 = 1) into LDS
    if (t < 64) {
      const unsigned target = SUBTGT * (unsigned)(((MAXIT - 1) >> 1) + 1);
      POLL_GROUPS(ph1a, ph1b, (Dsum + (size_t)TT * WPR * LSTR), target,
                  (unsigned)(MAXIT + 1), false, 0)
    }
    __syncthreads();
  }

  // ---- loss partial: sum u_bar * exp(-20c) * v_bar * c over own stripe ----
  float lacc = 0.f;
  for (int i = 0; i < 16; ++i) {
    int row = rB + 32 * i;
    const float* p = cb + (size_t)row * VV + cB * 8;
    f4 x0 = *(const f4*)p;
    f4 x1 = *(const f4*)(p + 4);
    float um = uf[row];
    float inner = 0.f;
#pragma unroll
    for (int e = 0; e < 4; ++e) inner = fmaf(vf[cB * 8 + e] * __expf(-20.f * x0[e]), x0[e], inner);
#pragma unroll
    for (int e = 0; e < 4; ++e) inner = fmaf(vf[cB * 8 + 4 + e] * __expf(-20.f * x1[e]), x1[e], inner);
    lacc = fmaf(um, inner, lacc);
  }
  lacc = red64(lacc);
  if ((t & 63) == 63) wred[t >> 6] = lacc;
  __syncthreads();
  if (t == 0) {
    float s = 0.f;
#pragma unroll
    for (int w = 0; w < 8; ++w) s += wred[w];
    lossp[b] = s;
  }
}

extern "C" __global__ void prep_kernel(u64* Dsum, float* errb, float* out) {
  int gid = threadIdx.x + blockIdx.x * 256;
  for (int i = gid; i < 2 * TT * WPR * LSTR; i += gridDim.x * 256) Dsum[i] = 0ull;
  if (gid < NCHK) errb[gid] = 0.f;
  if (gid == 0) out[0] = 0.f;
}

extern "C" __global__ void final_kernel(const float* __restrict__ lossp, float* __restrict__ out) {
  int t = threadIdx.x;  // 64 threads, one wave
  float s = 0.f;
  for (int i = t; i < NB; i += 64) s += lossp[i];
  s = red64(s);
  if (t == 63) out[0] = s * (100.0f / ((float)TT * (float)VV));
}

extern "C" void kernel_launch(void* const* d_in, const int* in_sizes, int n_in,
                              void* d_out, int out_size, void* d_ws, size_t ws_size,
                              hipStream_t stream) {
  const float* cost = (const float*)d_in[0];
  float* out = (float*)d_out;
  char* ws = (char*)d_ws;
  u64*   Dsum  = (u64*)ws;                 // 2*512*2*16 u64 = 262144 B (line-spread)
  float* errb  = (float*)(ws + 262144);    // 20 f32
  float* lossp = (float*)(ws + 262272);    // 250 f32

  prep_kernel<<<64, 256, 0, stream>>>(Dsum, errb, out);

  (void)hipFuncSetAttribute((const void*)sink_kernel,
                            hipFuncAttributeMaxDynamicSharedMemorySize, LDS_BYTES);
  void* args[] = {(void*)&cost, (void*)&Dsum, (void*)&errb, (void*)&lossp};
  (void)hipLaunchCooperativeKernel((const void*)sink_kernel, dim3(NB), dim3(NTHR),
                                   args, LDS_BYTES, stream);

  final_kernel<<<1, 64, 0, stream>>>(lossp, out);
}